// Round 12
// baseline (67.299 us; speedup 1.0000x reference)
//
#include <hip/hip_runtime.h>
#include <math.h>

#define BB 2
#define NN 1024
#define HH 4
#define F_IN 128
#define HID 32
#define TJ 64
#define NT (NN/TJ)     // 16 j-tiles, one u64 mask word each
#define NC 4           // j-chunks in score kernel
#define CT (NT/NC)     // 4 tiles per chunk

#define LOG2E 1.44269504f

typedef unsigned long long u64;
typedef _Float16 f16;
typedef _Float16 f16x8 __attribute__((ext_vector_type(8)));
typedef float f32x4 __attribute__((ext_vector_type(4)));

// ---- workspace layout (bytes) ----
#define WS_X    0              // f32 x [bh][n][k]              = 1048576
#define WS_D6   1048576        // f32 [bh][n] (0.6*log2e*Wa.x)  = 32768
#define WS_BITS 1081344        // u64 [b][n][NT]                = 262144
#define WS_XT   1343488        // f16 X^T [bh][k=32][n=1024]    = 524288
#define WS_P    1867776        // f16 P [bh][i][j]              = 16777216
#define WS_LS   18644992       // f32 lsum part [NC][bh][n]     = 131072
#define WS_PART 18776064       // f32 out part [NC][bh][n][32]  = 4194304

// ---------------- Kernel 1: proj (x=feat@W) + X^T(f16) + d6 + adjacency bit-pack
__global__ __launch_bounds__(128) void gat_proj_kernel(const float* __restrict__ feat,
        const float* __restrict__ W, const float* __restrict__ Wa, const int* __restrict__ adj,
        float* __restrict__ xout, f16* __restrict__ xt, float* __restrict__ d6,
        u64* __restrict__ bits) {
    const int RPB = 8;
    int blk = blockIdx.x;              // 0 .. BB*NN/8-1
    int b  = blk / (NN / RPB);
    int n0 = (blk % (NN / RPB)) * RPB;
    int t  = threadIdx.x;              // 0..127 -> output column h*32+k

    __shared__ float fs[RPB][F_IN];
    for (int e = t; e < RPB * F_IN; e += 128) {
        int r = e >> 7, f = e & 127;
        fs[r][f] = feat[((size_t)(b*NN + n0 + r))*F_IN + f];
    }
    __syncthreads();

    float acc[RPB];
#pragma unroll
    for (int r = 0; r < RPB; ++r) acc[r] = 0.f;
    for (int f = 0; f < F_IN; ++f) {
        float w = W[f*(HH*HID) + t];
#pragma unroll
        for (int r = 0; r < RPB; ++r) acc[r] = fmaf(fs[r][f], w, acc[r]);
    }

    int h = t >> 5, k = t & 31;
    int bh = b*HH + h;
    // x rows (f32, for score-kernel staging + xi scalar loads)
#pragma unroll
    for (int r = 0; r < RPB; ++r)
        xout[((size_t)bh*NN + n0 + r)*HID + k] = acc[r];
    // X^T f16: row (bh*32+k), cols n0..n0+7 — one 16B store per thread
    {
        f16x8 hv;
#pragma unroll
        for (int r = 0; r < RPB; ++r) hv[r] = (f16)acc[r];
        *(f16x8*)(xt + ((size_t)bh*HID + k)*NN + n0) = hv;
    }
    // d6 = 0.6*log2e*(x.Wa) per node
    float w_t = Wa[t];
#pragma unroll
    for (int r = 0; r < RPB; ++r) {
        float p = acc[r] * w_t;
#pragma unroll
        for (int off = 16; off >= 1; off >>= 1) p += __shfl_xor(p, off, 32);
        if (k == 0) d6[(size_t)bh*NN + n0 + r] = 0.6f * LOG2E * p;
    }
    // adjacency bit-pack for this block's 8 rows
#pragma unroll
    for (int r = 0; r < RPB; ++r) {
        const int* arow = adj + ((size_t)(b*NN + n0 + r))*NN;
        u64* brow = bits + ((size_t)(b*NN + n0 + r))*NT;
#pragma unroll
        for (int c0 = 0; c0 < NN; c0 += 128) {
            u64 m = __ballot(arow[c0 + t] > 0);
            if ((t & 63) == 0) brow[(c0 + t) >> 6] = m;
        }
    }
}

__device__ __forceinline__ float sload(float v) {
    return __uint_as_float(__builtin_amdgcn_readfirstlane(__float_as_uint(v)));
}

// ---------------- Kernel A: scores. 256 thr (4 waves), 2 rows/wave, j-chunked (NC=4).
// 4096 blocks -> 16K waves (8/SIMD). Writes P=f16 2^(e-8) and per-chunk f32 lsum.
__global__ __launch_bounds__(256) void gat_score_kernel(const float* __restrict__ x,
                                                        const float* __restrict__ d6,
                                                        const u64* __restrict__ bits,
                                                        const float* __restrict__ Wa,
                                                        f16* __restrict__ P,
                                                        float* __restrict__ lsp) {
    const int tid = threadIdx.x;
    const int w = __builtin_amdgcn_readfirstlane(tid >> 6);   // wave id 0..3
    const int l = tid & 63;
    const int blk = blockIdx.x;                // 0..4095
    const int bh = blk & 7;                    // XCD pin
    const int rest = blk >> 3;                 // 0..511
    const int jc = rest & (NC - 1);            // j-chunk
    const int i0 = (rest >> 2) << 3;           // 8 rows per block
    const int h = bh & (HH - 1);
    const int iA = i0 + 2*w, iB = iA + 1;

    const float* xbh = x  + (size_t)bh * NN * HID;
    const float* dbh = d6 + (size_t)bh * NN;
    const int b = bh >> 2;
    const u64* brA = bits + ((size_t)b*NN + iA) * NT;
    const u64* brB = bits + ((size_t)b*NN + iB) * NT;

    // wave-uniform row data -> SGPRs; fixed softmax shift -8 folded into ci
    float xiA[HID], xiB[HID], wa4[HID];
#pragma unroll
    for (int k = 0; k < HID; ++k) {
        xiA[k] = sload(xbh[(size_t)iA*HID + k]);
        xiB[k] = sload(xbh[(size_t)iB*HID + k]);
        wa4[k] = sload((0.4f * LOG2E) * Wa[h*HID + k]);
    }
    float ciA = sload(dbh[iA]) - 8.0f;
    float ciB = sload(dbh[iB]) - 8.0f;

    __shared__ float xs[2][TJ][36];     // 18.4 KB, pad 36 -> conflict-free b128

    float lsA = 0.f, lsB = 0.f;
    f16* prA = P + ((size_t)bh << 20) + (size_t)iA * NN;
    f16* prB = P + ((size_t)bh << 20) + (size_t)iB * NN;

    // staging: tile = 64 rows x 32 floats = 512 float4; 256 threads x 2 (R6-proven)
    const int r0 = tid >> 3,         q0 = (tid & 7) << 2;
    const int r1 = (tid + 256) >> 3, q1 = ((tid + 256) & 7) << 2;
    const float4* gsrc = (const float4*)xbh;
    const int t0 = jc * CT;                     // first tile of this chunk
    float4 pre0 = gsrc[t0*512 + tid];
    float4 pre1 = gsrc[t0*512 + tid + 256];

    for (int tt = 0; tt < CT; ++tt) {
        const int tg = t0 + tt;                 // global tile index
        const int bc = tt & 1;
        *(float4*)&xs[bc][r0][q0] = pre0;
        *(float4*)&xs[bc][r1][q1] = pre1;
        __syncthreads();
        if (tt + 1 < CT) {
            pre0 = gsrc[(tg + 1)*512 + tid];
            pre1 = gsrc[(tg + 1)*512 + tid + 256];
        }

        u64 wA = brA[tg], wB = brB[tg];
        const int j = tg*TJ + l;
        float dj = dbh[j];

        float4 xj4[8];
#pragma unroll
        for (int q = 0; q < 8; ++q) xj4[q] = *(const float4*)&xs[bc][l][4*q];

        float sA0 = 0.f, sA1 = 0.f, sA2 = 0.f, sA3 = 0.f;
        float sB0 = 0.f, sB1 = 0.f, sB2 = 0.f, sB3 = 0.f;
#pragma unroll
        for (int q = 0; q < 8; ++q) {
            float4 xv = xj4[q];
            float v;
            v = xiA[4*q+0] + xv.x; sA0 = fmaf(wa4[4*q+0], fabsf(v), sA0);
            v = xiA[4*q+1] + xv.y; sA1 = fmaf(wa4[4*q+1], fabsf(v), sA1);
            v = xiA[4*q+2] + xv.z; sA2 = fmaf(wa4[4*q+2], fabsf(v), sA2);
            v = xiA[4*q+3] + xv.w; sA3 = fmaf(wa4[4*q+3], fabsf(v), sA3);
            v = xiB[4*q+0] + xv.x; sB0 = fmaf(wa4[4*q+0], fabsf(v), sB0);
            v = xiB[4*q+1] + xv.y; sB1 = fmaf(wa4[4*q+1], fabsf(v), sB1);
            v = xiB[4*q+2] + xv.z; sB2 = fmaf(wa4[4*q+2], fabsf(v), sB2);
            v = xiB[4*q+3] + xv.w; sB3 = fmaf(wa4[4*q+3], fabsf(v), sB3);
        }
        float eA = (ciA + dj) + ((sA0 + sA1) + (sA2 + sA3));
        float eB = (ciB + dj) + ((sB0 + sB1) + (sB2 + sB3));
        float peA = exp2f(eA), peB = exp2f(eB);
        float pA, pB;
        asm("v_cndmask_b32 %0, 0, %1, %2" : "=v"(pA) : "v"(peA), "s"(wA));
        asm("v_cndmask_b32 %0, 0, %1, %2" : "=v"(pB) : "v"(peB), "s"(wB));
        lsA += pA;
        lsB += pB;
        prA[j] = (f16)pA;                       // coalesced 128B wave-store
        prB[j] = (f16)pB;
        __syncthreads();                        // protect xs before next overwrite
    }

    // per-chunk denominator partials
#pragma unroll
    for (int off = 32; off >= 1; off >>= 1) {
        lsA += __shfl_xor(lsA, off, 64);
        lsB += __shfl_xor(lsB, off, 64);
    }
    if (l == 0) {
        lsp[(size_t)jc*(8*NN) + bh*NN + iA] = lsA;
        lsp[(size_t)jc*(8*NN) + bh*NN + iB] = lsB;
    }
}

// ---------------- Kernel B: out_partial = P @ X  via MFMA f16.
// 1 wave/block; block = (bh, 16-row i-tile, 256-wide j-chunk); K-loop 8x(32 j).
// A-frag: lane l holds P[i0+(l&15)][jt*32+(l>>4)*8 + e], e=0..7 (16B contiguous).
// B-frag: lane l holds X[j=(l>>4)*8+e][k=(l&15)] = X^T[k][j...] (16B contiguous).
// C/D (HW-verified): col=lane&15, row=(lane>>4)*4+reg.
__global__ __launch_bounds__(64) void gat_agg_kernel(const f16* __restrict__ P,
                                                     const f16* __restrict__ xt,
                                                     float* __restrict__ part) {
    const int l = threadIdx.x;
    const int blk = blockIdx.x;                // 0..2047
    const int bh = blk & 7;                    // XCD pin (same as score kernel)
    const int rest = blk >> 3;                 // 0..255
    const int it = rest & 63;                  // i-tile
    const int jc = rest >> 6;                  // j-chunk 0..3
    const int i0 = it << 4;
    const int jbase = jc << 8;

    const f16* Pb  = P  + ((size_t)bh << 20);
    const f16* xtb = xt + (size_t)bh * HID * NN;

    f32x4 acc0 = {0.f, 0.f, 0.f, 0.f};
    f32x4 acc1 = {0.f, 0.f, 0.f, 0.f};
    const int lrow = l & 15, lslot = (l >> 4) << 3;

#pragma unroll
    for (int jt = 0; jt < 8; ++jt) {
        const int joff = jbase + jt*32 + lslot;
        f16x8 af = *(const f16x8*)(Pb  + (size_t)(i0 + lrow)*NN + joff);
        f16x8 b0 = *(const f16x8*)(xtb + (size_t)lrow*NN + joff);
        f16x8 b1 = *(const f16x8*)(xtb + (size_t)(16 + lrow)*NN + joff);
        acc0 = __builtin_amdgcn_mfma_f32_16x16x32_f16(af, b0, acc0, 0, 0, 0);
        acc1 = __builtin_amdgcn_mfma_f32_16x16x32_f16(af, b1, acc1, 0, 0, 0);
    }

    float* pb = part + ((size_t)(jc*8 + bh) << 15);   // [n][32] f32
#pragma unroll
    for (int r = 0; r < 4; ++r) {
        int row = i0 + ((l >> 4) << 2) + r;
        pb[(size_t)row*32 + lrow]      = acc0[r];
        pb[(size_t)row*32 + 16 + lrow] = acc1[r];
    }
}

// ---------------- Kernel C: out = (sum_jc part) / (sum_jc lsum), head-concat
__global__ __launch_bounds__(256) void gat_final_kernel(const float* __restrict__ part,
                                                        const float* __restrict__ lsp,
                                                        float* __restrict__ out) {
    int t = blockIdx.x * 256 + threadIdx.x;    // 0 .. 262143
    int k  = t & 31;
    int n  = (t >> 5) & (NN - 1);
    int bh = t >> 15;
    int b = bh >> 2, h = bh & 3;
    float s = 0.f, ls = 0.f;
#pragma unroll
    for (int jc = 0; jc < NC; ++jc) {
        s  += part[((size_t)(jc*8 + bh) << 15) + (n << 5) + k];
        ls += lsp[(size_t)jc*(8*NN) + bh*NN + n];
    }
    out[((size_t)(b*NN + n))*(HH*HID) + h*HID + k] = s / ls;
}

extern "C" void kernel_launch(void* const* d_in, const int* in_sizes, int n_in,
                              void* d_out, int out_size, void* d_ws, size_t ws_size,
                              hipStream_t stream) {
    const float* node_feat = (const float*)d_in[0];
    const int*   adj_mtx   = (const int*)d_in[1];
    const float* W         = (const float*)d_in[2];
    const float* Wa        = (const float*)d_in[3];
    float* out = (float*)d_out;

    char* ws = (char*)d_ws;
    float* x_ws  = (float*)(ws + WS_X);
    float* d6_ws = (float*)(ws + WS_D6);
    u64*   bits  = (u64*)(ws + WS_BITS);
    f16*   xt_ws = (f16*)(ws + WS_XT);
    f16*   P_ws  = (f16*)(ws + WS_P);
    float* ls_ws = (float*)(ws + WS_LS);
    float* pt_ws = (float*)(ws + WS_PART);

    hipLaunchKernelGGL(gat_proj_kernel, dim3(BB*NN/8), dim3(128), 0, stream,
                       node_feat, W, Wa, adj_mtx, x_ws, xt_ws, d6_ws, bits);
    hipLaunchKernelGGL(gat_score_kernel, dim3(BB*HH*NN/8 * NC), dim3(256), 0, stream,
                       x_ws, d6_ws, bits, Wa, P_ws, ls_ws);
    hipLaunchKernelGGL(gat_agg_kernel, dim3(8 * 64 * NC), dim3(64), 0, stream,
                       P_ws, xt_ws, pt_ws);
    hipLaunchKernelGGL(gat_final_kernel, dim3(BB*NN*HH*HID/256), dim3(256), 0, stream,
                       pt_ws, ls_ws, out);
}

// Round 13
// 49.430 us; speedup vs baseline: 1.3615x; 1.3615x over previous
//
#include <hip/hip_runtime.h>
#include <math.h>

#define BB 2
#define NN 1024
#define HH 4
#define F_IN 128
#define HID 32
#define TJ 64
#define NT (NN/TJ)     // 16 j-tiles, one u64 mask word each
#define NC 4           // j-chunks in score kernel
#define CT (NT/NC)     // 4 tiles per chunk

#define LOG2E 1.44269504f

typedef unsigned long long u64;
typedef _Float16 f16;
typedef _Float16 f16x8 __attribute__((ext_vector_type(8)));
typedef _Float16 f16x4 __attribute__((ext_vector_type(4)));
typedef float f32x4 __attribute__((ext_vector_type(4)));

// ---- workspace layout (bytes) ----
#define WS_X    0              // f32 x [bh][n][k]              = 1048576
#define WS_D6   1048576        // f32 [bh][n] (0.6*log2e*Wa.x)  = 32768
#define WS_BITS 1081344        // u64 [b][n][NT]                = 262144
#define WS_XT   1343488        // f16 X^T [bh][k=32][n=1024]    = 524288
#define WS_P    1867776        // f16 P [bh][i][j]              = 16777216
#define WS_LS   18644992       // f32 lsum part [NC][bh][n]     = 131072
#define WS_PART 18776064       // f32 out part [NC][bh][n][32]  = 4194304

// ---------------- Kernel 0: adjacency bit-pack (standalone streaming, R1-style)
__global__ __launch_bounds__(256) void gat_pack_kernel(const int* __restrict__ adj,
                                                       u64* __restrict__ bits) {
    int gid = blockIdx.x * 256 + threadIdx.x;    // 0 .. B*N*N-1
    u64 m = __ballot(adj[gid] > 0);
    if ((threadIdx.x & 63) == 0) bits[gid >> 6] = m;
}

// ---------------- Kernel 1: proj (x=feat@W) + X^T(f16) + d6.  RPB=4 -> 512 blocks.
__global__ __launch_bounds__(128) void gat_proj_kernel(const float* __restrict__ feat,
        const float* __restrict__ W, const float* __restrict__ Wa,
        float* __restrict__ xout, f16* __restrict__ xt, float* __restrict__ d6) {
    const int RPB = 4;
    int blk = blockIdx.x;              // 0 .. BB*NN/4-1
    int b  = blk / (NN / RPB);
    int n0 = (blk % (NN / RPB)) * RPB;
    int t  = threadIdx.x;              // 0..127 -> output column h*32+k

    __shared__ float fs[RPB][F_IN];
#pragma unroll
    for (int e = 0; e < RPB; ++e) {
        int idx = e * 128 + t;
        int r = idx >> 7, f = idx & 127;
        fs[r][f] = feat[((size_t)(b*NN + n0 + r))*F_IN + f];
    }
    __syncthreads();

    float acc[RPB];
#pragma unroll
    for (int r = 0; r < RPB; ++r) acc[r] = 0.f;
    for (int f = 0; f < F_IN; ++f) {
        float w = W[f*(HH*HID) + t];
#pragma unroll
        for (int r = 0; r < RPB; ++r) acc[r] = fmaf(fs[r][f], w, acc[r]);
    }

    int h = t >> 5, k = t & 31;
    int bh = b*HH + h;
    // x rows (f32, for score-kernel staging + xi scalar loads)
#pragma unroll
    for (int r = 0; r < RPB; ++r)
        xout[((size_t)bh*NN + n0 + r)*HID + k] = acc[r];
    // X^T f16: row (bh*32+k), cols n0..n0+3 — one 8B store per thread
    {
        f16x4 hv;
#pragma unroll
        for (int r = 0; r < RPB; ++r) hv[r] = (f16)acc[r];
        *(f16x4*)(xt + ((size_t)bh*HID + k)*NN + n0) = hv;
    }
    // d6 = 0.6*log2e*(x.Wa) per node
    float w_t = Wa[t];
#pragma unroll
    for (int r = 0; r < RPB; ++r) {
        float p = acc[r] * w_t;
#pragma unroll
        for (int off = 16; off >= 1; off >>= 1) p += __shfl_xor(p, off, 32);
        if (k == 0) d6[(size_t)bh*NN + n0 + r] = 0.6f * LOG2E * p;
    }
}

__device__ __forceinline__ float sload(float v) {
    return __uint_as_float(__builtin_amdgcn_readfirstlane(__float_as_uint(v)));
}

// ---------------- Kernel A: scores (R12-verbatim). 256 thr (4 waves), 2 rows/wave,
// j-chunked (NC=4). 4096 blocks -> 16K waves. Writes P=f16 2^(e-8) + f32 lsum partials.
__global__ __launch_bounds__(256) void gat_score_kernel(const float* __restrict__ x,
                                                        const float* __restrict__ d6,
                                                        const u64* __restrict__ bits,
                                                        const float* __restrict__ Wa,
                                                        f16* __restrict__ P,
                                                        float* __restrict__ lsp) {
    const int tid = threadIdx.x;
    const int w = __builtin_amdgcn_readfirstlane(tid >> 6);   // wave id 0..3
    const int l = tid & 63;
    const int blk = blockIdx.x;                // 0..4095
    const int bh = blk & 7;                    // XCD pin
    const int rest = blk >> 3;                 // 0..511
    const int jc = rest & (NC - 1);            // j-chunk
    const int i0 = (rest >> 2) << 3;           // 8 rows per block
    const int h = bh & (HH - 1);
    const int iA = i0 + 2*w, iB = iA + 1;

    const float* xbh = x  + (size_t)bh * NN * HID;
    const float* dbh = d6 + (size_t)bh * NN;
    const int b = bh >> 2;
    const u64* brA = bits + ((size_t)b*NN + iA) * NT;
    const u64* brB = bits + ((size_t)b*NN + iB) * NT;

    // wave-uniform row data -> SGPRs; fixed softmax shift -8 folded into ci
    float xiA[HID], xiB[HID], wa4[HID];
#pragma unroll
    for (int k = 0; k < HID; ++k) {
        xiA[k] = sload(xbh[(size_t)iA*HID + k]);
        xiB[k] = sload(xbh[(size_t)iB*HID + k]);
        wa4[k] = sload((0.4f * LOG2E) * Wa[h*HID + k]);
    }
    float ciA = sload(dbh[iA]) - 8.0f;
    float ciB = sload(dbh[iB]) - 8.0f;

    __shared__ float xs[2][TJ][36];     // 18.4 KB, pad 36 -> conflict-free b128

    float lsA = 0.f, lsB = 0.f;
    f16* prA = P + ((size_t)bh << 20) + (size_t)iA * NN;
    f16* prB = P + ((size_t)bh << 20) + (size_t)iB * NN;

    // staging: tile = 64 rows x 32 floats = 512 float4; 256 threads x 2 (R6-proven)
    const int r0 = tid >> 3,         q0 = (tid & 7) << 2;
    const int r1 = (tid + 256) >> 3, q1 = ((tid + 256) & 7) << 2;
    const float4* gsrc = (const float4*)xbh;
    const int t0 = jc * CT;                     // first tile of this chunk
    float4 pre0 = gsrc[t0*512 + tid];
    float4 pre1 = gsrc[t0*512 + tid + 256];

    for (int tt = 0; tt < CT; ++tt) {
        const int tg = t0 + tt;                 // global tile index
        const int bc = tt & 1;
        *(float4*)&xs[bc][r0][q0] = pre0;
        *(float4*)&xs[bc][r1][q1] = pre1;
        __syncthreads();
        if (tt + 1 < CT) {
            pre0 = gsrc[(tg + 1)*512 + tid];
            pre1 = gsrc[(tg + 1)*512 + tid + 256];
        }

        u64 wA = brA[tg], wB = brB[tg];
        const int j = tg*TJ + l;
        float dj = dbh[j];

        float4 xj4[8];
#pragma unroll
        for (int q = 0; q < 8; ++q) xj4[q] = *(const float4*)&xs[bc][l][4*q];

        float sA0 = 0.f, sA1 = 0.f, sA2 = 0.f, sA3 = 0.f;
        float sB0 = 0.f, sB1 = 0.f, sB2 = 0.f, sB3 = 0.f;
#pragma unroll
        for (int q = 0; q < 8; ++q) {
            float4 xv = xj4[q];
            float v;
            v = xiA[4*q+0] + xv.x; sA0 = fmaf(wa4[4*q+0], fabsf(v), sA0);
            v = xiA[4*q+1] + xv.y; sA1 = fmaf(wa4[4*q+1], fabsf(v), sA1);
            v = xiA[4*q+2] + xv.z; sA2 = fmaf(wa4[4*q+2], fabsf(v), sA2);
            v = xiA[4*q+3] + xv.w; sA3 = fmaf(wa4[4*q+3], fabsf(v), sA3);
            v = xiB[4*q+0] + xv.x; sB0 = fmaf(wa4[4*q+0], fabsf(v), sB0);
            v = xiB[4*q+1] + xv.y; sB1 = fmaf(wa4[4*q+1], fabsf(v), sB1);
            v = xiB[4*q+2] + xv.z; sB2 = fmaf(wa4[4*q+2], fabsf(v), sB2);
            v = xiB[4*q+3] + xv.w; sB3 = fmaf(wa4[4*q+3], fabsf(v), sB3);
        }
        float eA = (ciA + dj) + ((sA0 + sA1) + (sA2 + sA3));
        float eB = (ciB + dj) + ((sB0 + sB1) + (sB2 + sB3));
        float peA = exp2f(eA), peB = exp2f(eB);
        float pA, pB;
        asm("v_cndmask_b32 %0, 0, %1, %2" : "=v"(pA) : "v"(peA), "s"(wA));
        asm("v_cndmask_b32 %0, 0, %1, %2" : "=v"(pB) : "v"(peB), "s"(wB));
        lsA += pA;
        lsB += pB;
        prA[j] = (f16)pA;                       // coalesced 128B wave-store
        prB[j] = (f16)pB;
        __syncthreads();                        // protect xs before next overwrite
    }

    // per-chunk denominator partials
#pragma unroll
    for (int off = 32; off >= 1; off >>= 1) {
        lsA += __shfl_xor(lsA, off, 64);
        lsB += __shfl_xor(lsB, off, 64);
    }
    if (l == 0) {
        lsp[(size_t)jc*(8*NN) + bh*NN + iA] = lsA;
        lsp[(size_t)jc*(8*NN) + bh*NN + iB] = lsB;
    }
}

// ---------------- Kernel B: out_partial = P @ X via MFMA f16 (R12-verbatim, validated).
__global__ __launch_bounds__(64) void gat_agg_kernel(const f16* __restrict__ P,
                                                     const f16* __restrict__ xt,
                                                     float* __restrict__ part) {
    const int l = threadIdx.x;
    const int blk = blockIdx.x;                // 0..2047
    const int bh = blk & 7;                    // XCD pin (same as score kernel)
    const int rest = blk >> 3;                 // 0..255
    const int it = rest & 63;                  // i-tile
    const int jc = rest >> 6;                  // j-chunk 0..3
    const int i0 = it << 4;
    const int jbase = jc << 8;

    const f16* Pb  = P  + ((size_t)bh << 20);
    const f16* xtb = xt + (size_t)bh * HID * NN;

    f32x4 acc0 = {0.f, 0.f, 0.f, 0.f};
    f32x4 acc1 = {0.f, 0.f, 0.f, 0.f};
    const int lrow = l & 15, lslot = (l >> 4) << 3;

#pragma unroll
    for (int jt = 0; jt < 8; ++jt) {
        const int joff = jbase + jt*32 + lslot;
        f16x8 af = *(const f16x8*)(Pb  + (size_t)(i0 + lrow)*NN + joff);
        f16x8 b0 = *(const f16x8*)(xtb + (size_t)lrow*NN + joff);
        f16x8 b1 = *(const f16x8*)(xtb + (size_t)(16 + lrow)*NN + joff);
        acc0 = __builtin_amdgcn_mfma_f32_16x16x32_f16(af, b0, acc0, 0, 0, 0);
        acc1 = __builtin_amdgcn_mfma_f32_16x16x32_f16(af, b1, acc1, 0, 0, 0);
    }

    float* pb = part + ((size_t)(jc*8 + bh) << 15);   // [n][32] f32
#pragma unroll
    for (int r = 0; r < 4; ++r) {
        int row = i0 + ((l >> 4) << 2) + r;
        pb[(size_t)row*32 + lrow]      = acc0[r];
        pb[(size_t)row*32 + 16 + lrow] = acc1[r];
    }
}

// ---------------- Kernel C: out = (sum_jc part) / (sum_jc lsum), head-concat (R12-verbatim)
__global__ __launch_bounds__(256) void gat_final_kernel(const float* __restrict__ part,
                                                        const float* __restrict__ lsp,
                                                        float* __restrict__ out) {
    int t = blockIdx.x * 256 + threadIdx.x;    // 0 .. 262143
    int k  = t & 31;
    int n  = (t >> 5) & (NN - 1);
    int bh = t >> 15;
    int b = bh >> 2, h = bh & 3;
    float s = 0.f, ls = 0.f;
#pragma unroll
    for (int jc = 0; jc < NC; ++jc) {
        s  += part[((size_t)(jc*8 + bh) << 15) + (n << 5) + k];
        ls += lsp[(size_t)jc*(8*NN) + bh*NN + n];
    }
    out[((size_t)(b*NN + n))*(HH*HID) + h*HID + k] = s / ls;
}

extern "C" void kernel_launch(void* const* d_in, const int* in_sizes, int n_in,
                              void* d_out, int out_size, void* d_ws, size_t ws_size,
                              hipStream_t stream) {
    const float* node_feat = (const float*)d_in[0];
    const int*   adj_mtx   = (const int*)d_in[1];
    const float* W         = (const float*)d_in[2];
    const float* Wa        = (const float*)d_in[3];
    float* out = (float*)d_out;

    char* ws = (char*)d_ws;
    float* x_ws  = (float*)(ws + WS_X);
    float* d6_ws = (float*)(ws + WS_D6);
    u64*   bits  = (u64*)(ws + WS_BITS);
    f16*   xt_ws = (f16*)(ws + WS_XT);
    f16*   P_ws  = (f16*)(ws + WS_P);
    float* ls_ws = (float*)(ws + WS_LS);
    float* pt_ws = (float*)(ws + WS_PART);

    hipLaunchKernelGGL(gat_pack_kernel, dim3(BB*NN*NN/256), dim3(256), 0, stream,
                       adj_mtx, bits);
    hipLaunchKernelGGL(gat_proj_kernel, dim3(BB*NN/4), dim3(128), 0, stream,
                       node_feat, W, Wa, x_ws, xt_ws, d6_ws);
    hipLaunchKernelGGL(gat_score_kernel, dim3(BB*HH*NN/8 * NC), dim3(256), 0, stream,
                       x_ws, d6_ws, bits, Wa, P_ws, ls_ws);
    hipLaunchKernelGGL(gat_agg_kernel, dim3(8 * 64 * NC), dim3(64), 0, stream,
                       P_ws, xt_ws, pt_ws);
    hipLaunchKernelGGL(gat_final_kernel, dim3(BB*NN*HH*HID/256), dim3(256), 0, stream,
                       pt_ws, ls_ws, out);
}

// Round 14
// 42.334 us; speedup vs baseline: 1.5897x; 1.1676x over previous
//
#include <hip/hip_runtime.h>
#include <math.h>

#define BB 2
#define NN 1024
#define HH 4
#define F_IN 128
#define HID 32
#define TJ 64
#define NT (NN/TJ)     // 16 j-tiles
#define NC 2           // j-chunks in score kernel
#define CT (NT/NC)     // 8 tiles per chunk

#define LOG2E 1.44269504f

typedef unsigned long long u64;
typedef _Float16 f16;
typedef _Float16 f16x8 __attribute__((ext_vector_type(8)));
typedef _Float16 f16x4 __attribute__((ext_vector_type(4)));
typedef float f32x4 __attribute__((ext_vector_type(4)));

// ---- workspace layout (bytes) ----
#define WS_X    0              // f32 x [bh][n][k]              = 1048576
#define WS_D6   1048576        // f32 [bh][n] (0.6*log2e*Wa.x)  = 32768
#define WS_XT   1081344        // f16 X^T [bh][k=32][n=1024]    = 524288
#define WS_P    1605632        // f16 P [bh][i][j]              = 16777216
#define WS_LS   18382848       // f32 lsum part [NC][bh][n]     = 65536

// ---------------- Kernel 1: proj (x=feat@W) + X^T(f16) + d6.  RPB=4, 512 blocks (R13-verbatim)
__global__ __launch_bounds__(128) void gat_proj_kernel(const float* __restrict__ feat,
        const float* __restrict__ W, const float* __restrict__ Wa,
        float* __restrict__ xout, f16* __restrict__ xt, float* __restrict__ d6) {
    const int RPB = 4;
    int blk = blockIdx.x;              // 0 .. BB*NN/4-1
    int b  = blk / (NN / RPB);
    int n0 = (blk % (NN / RPB)) * RPB;
    int t  = threadIdx.x;              // 0..127 -> output column h*32+k

    __shared__ float fs[RPB][F_IN];
#pragma unroll
    for (int e = 0; e < RPB; ++e) {
        int idx = e * 128 + t;
        int r = idx >> 7, f = idx & 127;
        fs[r][f] = feat[((size_t)(b*NN + n0 + r))*F_IN + f];
    }
    __syncthreads();

    float acc[RPB];
#pragma unroll
    for (int r = 0; r < RPB; ++r) acc[r] = 0.f;
    for (int f = 0; f < F_IN; ++f) {
        float w = W[f*(HH*HID) + t];
#pragma unroll
        for (int r = 0; r < RPB; ++r) acc[r] = fmaf(fs[r][f], w, acc[r]);
    }

    int h = t >> 5, k = t & 31;
    int bh = b*HH + h;
#pragma unroll
    for (int r = 0; r < RPB; ++r)
        xout[((size_t)bh*NN + n0 + r)*HID + k] = acc[r];
    {
        f16x4 hv;
#pragma unroll
        for (int r = 0; r < RPB; ++r) hv[r] = (f16)acc[r];
        *(f16x4*)(xt + ((size_t)bh*HID + k)*NN + n0) = hv;
    }
    float w_t = Wa[t];
#pragma unroll
    for (int r = 0; r < RPB; ++r) {
        float p = acc[r] * w_t;
#pragma unroll
        for (int off = 16; off >= 1; off >>= 1) p += __shfl_xor(p, off, 32);
        if (k == 0) d6[(size_t)bh*NN + n0 + r] = 0.6f * LOG2E * p;
    }
}

__device__ __forceinline__ float sload(float v) {
    return __uint_as_float(__builtin_amdgcn_readfirstlane(__float_as_uint(v)));
}

// ---------------- Kernel A: scores. 256 thr (4 waves), 2 rows/wave, NC=2 j-chunks.
// 2048 blocks -> 8192 waves (8/SIMD at ~60 VGPR). Inline adjacency ballot (no bits buf).
// Prologue via float4 loads + readfirstlane. Writes P=f16 2^(e-8) + f32 lsum partials.
__global__ __launch_bounds__(256) void gat_score_kernel(const float* __restrict__ x,
                                                        const float* __restrict__ d6,
                                                        const int* __restrict__ adj,
                                                        const float* __restrict__ Wa,
                                                        f16* __restrict__ P,
                                                        float* __restrict__ lsp) {
    const int tid = threadIdx.x;
    const int w = __builtin_amdgcn_readfirstlane(tid >> 6);   // wave id 0..3
    const int l = tid & 63;
    const int blk = blockIdx.x;                // 0..2047
    const int bh = blk & 7;                    // XCD pin
    const int rest = blk >> 3;                 // 0..255
    const int jc = rest & (NC - 1);            // j-chunk 0..1
    const int i0 = (rest >> 1) << 3;           // 8 rows per block
    const int h = bh & (HH - 1), b = bh >> 2;
    const int iA = i0 + 2*w, iB = iA + 1;

    const float* xbh = x  + (size_t)bh * NN * HID;
    const float* dbh = d6 + (size_t)bh * NN;
    const int* adjA = adj + ((size_t)b*NN + iA) * NN;
    const int* adjB = adj + ((size_t)b*NN + iB) * NN;

    // prologue: 20 wave-uniform float4 loads -> readfirstlane to SGPRs
    float xiA[HID], xiB[HID], wa4[HID];
    {
        const float4* xAv = (const float4*)(xbh + (size_t)iA*HID);
        const float4* xBv = (const float4*)(xbh + (size_t)iB*HID);
        const float4* wav = (const float4*)(Wa + h*HID);
#pragma unroll
        for (int q = 0; q < 8; ++q) {
            float4 a = xAv[q], bq = xBv[q], wv = wav[q];
            xiA[4*q+0] = sload(a.x);  xiA[4*q+1] = sload(a.y);
            xiA[4*q+2] = sload(a.z);  xiA[4*q+3] = sload(a.w);
            xiB[4*q+0] = sload(bq.x); xiB[4*q+1] = sload(bq.y);
            xiB[4*q+2] = sload(bq.z); xiB[4*q+3] = sload(bq.w);
            wa4[4*q+0] = sload((0.4f*LOG2E)*wv.x); wa4[4*q+1] = sload((0.4f*LOG2E)*wv.y);
            wa4[4*q+2] = sload((0.4f*LOG2E)*wv.z); wa4[4*q+3] = sload((0.4f*LOG2E)*wv.w);
        }
    }
    float ciA = sload(dbh[iA]) - 8.0f;         // fixed softmax shift -8
    float ciB = sload(dbh[iB]) - 8.0f;

    __shared__ float xs[2][TJ][36];     // 18.4 KB, pad 36 -> conflict-free b128

    float lsA = 0.f, lsB = 0.f;
    f16* prA = P + ((size_t)bh << 20) + (size_t)iA * NN;
    f16* prB = P + ((size_t)bh << 20) + (size_t)iB * NN;

    // staging: tile = 64 rows x 32 floats = 512 float4; 256 threads x 2 (R6-proven dbuf)
    const int r0 = tid >> 3,         q0 = (tid & 7) << 2;
    const int r1 = (tid + 256) >> 3, q1 = ((tid + 256) & 7) << 2;
    const float4* gsrc = (const float4*)xbh;
    const int t0 = jc * CT;
    float4 pre0 = gsrc[t0*512 + tid];
    float4 pre1 = gsrc[t0*512 + tid + 256];

    for (int tt = 0; tt < CT; ++tt) {
        const int tg = t0 + tt;
        const int bc = tt & 1;
        *(float4*)&xs[bc][r0][q0] = pre0;
        *(float4*)&xs[bc][r1][q1] = pre1;
        __syncthreads();
        if (tt + 1 < CT) {
            pre0 = gsrc[(tg + 1)*512 + tid];
            pre1 = gsrc[(tg + 1)*512 + tid + 256];
        }

        const int j = tg*TJ + l;
        u64 wA = __ballot(adjA[j] > 0);         // inline mask (replaces bits buffer)
        u64 wB = __ballot(adjB[j] > 0);
        float dj = dbh[j];

        float4 xj4[8];
#pragma unroll
        for (int q = 0; q < 8; ++q) xj4[q] = *(const float4*)&xs[bc][l][4*q];

        float sA0 = 0.f, sA1 = 0.f, sA2 = 0.f, sA3 = 0.f;
        float sB0 = 0.f, sB1 = 0.f, sB2 = 0.f, sB3 = 0.f;
#pragma unroll
        for (int q = 0; q < 8; ++q) {
            float4 xv = xj4[q];
            float v;
            v = xiA[4*q+0] + xv.x; sA0 = fmaf(wa4[4*q+0], fabsf(v), sA0);
            v = xiA[4*q+1] + xv.y; sA1 = fmaf(wa4[4*q+1], fabsf(v), sA1);
            v = xiA[4*q+2] + xv.z; sA2 = fmaf(wa4[4*q+2], fabsf(v), sA2);
            v = xiA[4*q+3] + xv.w; sA3 = fmaf(wa4[4*q+3], fabsf(v), sA3);
            v = xiB[4*q+0] + xv.x; sB0 = fmaf(wa4[4*q+0], fabsf(v), sB0);
            v = xiB[4*q+1] + xv.y; sB1 = fmaf(wa4[4*q+1], fabsf(v), sB1);
            v = xiB[4*q+2] + xv.z; sB2 = fmaf(wa4[4*q+2], fabsf(v), sB2);
            v = xiB[4*q+3] + xv.w; sB3 = fmaf(wa4[4*q+3], fabsf(v), sB3);
        }
        float eA = (ciA + dj) + ((sA0 + sA1) + (sA2 + sA3));
        float eB = (ciB + dj) + ((sB0 + sB1) + (sB2 + sB3));
        float peA = exp2f(eA), peB = exp2f(eB);
        float pA, pB;
        asm("v_cndmask_b32 %0, 0, %1, %2" : "=v"(pA) : "v"(peA), "s"(wA));
        asm("v_cndmask_b32 %0, 0, %1, %2" : "=v"(pB) : "v"(peB), "s"(wB));
        lsA += pA;
        lsB += pB;
        prA[j] = (f16)pA;                       // coalesced 128B wave-store
        prB[j] = (f16)pB;
    }

    // per-chunk denominator partials
#pragma unroll
    for (int off = 32; off >= 1; off >>= 1) {
        lsA += __shfl_xor(lsA, off, 64);
        lsB += __shfl_xor(lsB, off, 64);
    }
    if (l == 0) {
        lsp[(size_t)jc*(8*NN) + bh*NN + iA] = lsA;
        lsp[(size_t)jc*(8*NN) + bh*NN + iB] = lsB;
    }
}

// ---------------- Kernel B: out = (P @ X) / lsum via MFMA f16, full K=1024.
// 512 blocks x 1 wave: (bh, 16-row i-tile). Fragment mapping R12-validated.
__global__ __launch_bounds__(64) void gat_agg_kernel(const f16* __restrict__ P,
                                                     const f16* __restrict__ xt,
                                                     const float* __restrict__ lsp,
                                                     float* __restrict__ out) {
    const int l = threadIdx.x;
    const int blk = blockIdx.x;                // 0..511
    const int bh = blk & 7;                    // XCD pin (same as score)
    const int it = blk >> 3;                   // i-tile 0..63
    const int i0 = it << 4;
    const int b = bh >> 2, h = bh & 3;

    const f16* Pb  = P  + ((size_t)bh << 20);
    const f16* xtb = xt + (size_t)bh * HID * NN;

    f32x4 acc0 = {0.f, 0.f, 0.f, 0.f};
    f32x4 acc1 = {0.f, 0.f, 0.f, 0.f};
    const int lrow = l & 15, lslot = (l >> 4) << 3;

#pragma unroll
    for (int jt = 0; jt < 32; ++jt) {
        const int joff = jt*32 + lslot;
        f16x8 af = *(const f16x8*)(Pb  + (size_t)(i0 + lrow)*NN + joff);
        f16x8 b0 = *(const f16x8*)(xtb + (size_t)lrow*NN + joff);
        f16x8 b1 = *(const f16x8*)(xtb + (size_t)(16 + lrow)*NN + joff);
        acc0 = __builtin_amdgcn_mfma_f32_16x16x32_f16(af, b0, acc0, 0, 0, 0);
        acc1 = __builtin_amdgcn_mfma_f32_16x16x32_f16(af, b1, acc1, 0, 0, 0);
    }

    // C/D mapping (HW-verified): col=lane&15, row=(lane>>4)*4+reg
#pragma unroll
    for (int r = 0; r < 4; ++r) {
        int row = i0 + ((l >> 4) << 2) + r;
        float ls = lsp[bh*NN + row] + lsp[8*NN + bh*NN + row];   // jc=0 + jc=1
        float inv = 1.0f / ls;
        float* orow = out + ((size_t)(b*NN + row))*(HH*HID) + h*HID;
        orow[lrow]      = acc0[r] * inv;
        orow[16 + lrow] = acc1[r] * inv;
    }
}

extern "C" void kernel_launch(void* const* d_in, const int* in_sizes, int n_in,
                              void* d_out, int out_size, void* d_ws, size_t ws_size,
                              hipStream_t stream) {
    const float* node_feat = (const float*)d_in[0];
    const int*   adj_mtx   = (const int*)d_in[1];
    const float* W         = (const float*)d_in[2];
    const float* Wa        = (const float*)d_in[3];
    float* out = (float*)d_out;

    char* ws = (char*)d_ws;
    float* x_ws  = (float*)(ws + WS_X);
    float* d6_ws = (float*)(ws + WS_D6);
    f16*   xt_ws = (f16*)(ws + WS_XT);
    f16*   P_ws  = (f16*)(ws + WS_P);
    float* ls_ws = (float*)(ws + WS_LS);

    hipLaunchKernelGGL(gat_proj_kernel, dim3(BB*NN/4), dim3(128), 0, stream,
                       node_feat, W, Wa, x_ws, xt_ws, d6_ws);
    hipLaunchKernelGGL(gat_score_kernel, dim3(BB*HH*NN/8 * NC), dim3(256), 0, stream,
                       x_ws, d6_ws, adj_mtx, Wa, P_ws, ls_ws);
    hipLaunchKernelGGL(gat_agg_kernel, dim3(8 * 64), dim3(64), 0, stream,
                       P_ws, xt_ws, ls_ws, out);
}

// Round 15
// 39.812 us; speedup vs baseline: 1.6904x; 1.0634x over previous
//
#include <hip/hip_runtime.h>
#include <math.h>

#define BB 2
#define NN 1024
#define HH 4
#define F_IN 128
#define HID 32
#define TJ 64
#define NT 16
#define NC 2           // j-chunks
#define CT (NT/NC)     // 8 tiles per chunk

#define LOG2E 1.44269504f

typedef unsigned long long u64;
typedef unsigned int u32;
typedef _Float16 f16;
typedef _Float16 h2   __attribute__((ext_vector_type(2)));
typedef _Float16 f16x4 __attribute__((ext_vector_type(4)));
typedef _Float16 f16x8 __attribute__((ext_vector_type(8)));
typedef float f32x4 __attribute__((ext_vector_type(4)));

// ---- workspace layout (bytes) ----
#define WS_XH  0           // f16 x  [bh][n][k=32]   = 524288
#define WS_D6  524288      // f32 d6 [bh][n]         = 32768
#define WS_XT  557056      // f16 X^T[bh][k=32][n]   = 524288
#define WS_P   1081344     // f16 P  [bh][i][j]      = 16777216
#define WS_LS  17858560    // f32 lsum [NC][bh][n]   = 65536

#if __has_builtin(__builtin_amdgcn_fdot2)
#define FDOT2(a, b, c) __builtin_amdgcn_fdot2((a), (b), (c), false)
#else
static __device__ __forceinline__ float FDOT2(h2 a, h2 b, float c) {
    return fmaf((float)a[0], (float)b[0], fmaf((float)a[1], (float)b[1], c));
}
#endif

template <typename D, typename S>
static __device__ __forceinline__ D bcast(S s) { return __builtin_bit_cast(D, s); }

// ---------------- Kernel 1: proj (x=feat@W) -> xh(f16 [n][k]) + xt(f16 [k][n]) + d6
__global__ __launch_bounds__(128) void gat_proj_kernel(const float* __restrict__ feat,
        const float* __restrict__ W, const float* __restrict__ Wa,
        f16* __restrict__ xh, f16* __restrict__ xt, float* __restrict__ d6) {
    const int RPB = 4;
    int blk = blockIdx.x;              // 0 .. BB*NN/4-1
    int b  = blk / (NN / RPB);
    int n0 = (blk % (NN / RPB)) * RPB;
    int t  = threadIdx.x;              // 0..127 -> output column h*32+k

    __shared__ float fs[RPB][F_IN];
#pragma unroll
    for (int e = 0; e < RPB; ++e) {
        int idx = e * 128 + t;
        int r = idx >> 7, f = idx & 127;
        fs[r][f] = feat[((size_t)(b*NN + n0 + r))*F_IN + f];
    }
    __syncthreads();

    float acc[RPB];
#pragma unroll
    for (int r = 0; r < RPB; ++r) acc[r] = 0.f;
    for (int f = 0; f < F_IN; ++f) {
        float w = W[f*(HH*HID) + t];
#pragma unroll
        for (int r = 0; r < RPB; ++r) acc[r] = fmaf(fs[r][f], w, acc[r]);
    }

    int h = t >> 5, k = t & 31;
    int bh = b*HH + h;
    // xh f16 row-major (score kernel's xi/xj source)
#pragma unroll
    for (int r = 0; r < RPB; ++r)
        xh[((size_t)bh*NN + n0 + r)*HID + k] = (f16)acc[r];
    // xt f16 col-major (MFMA B operand)
    {
        f16x4 hv;
#pragma unroll
        for (int r = 0; r < RPB; ++r) hv[r] = (f16)acc[r];
        *(f16x4*)(xt + ((size_t)bh*HID + k)*NN + n0) = hv;
    }
    // d6 = 0.6*log2e*(x.Wa)
    float w_t = Wa[t];
#pragma unroll
    for (int r = 0; r < RPB; ++r) {
        float p = acc[r] * w_t;
#pragma unroll
        for (int off = 16; off >= 1; off >>= 1) p += __shfl_xor(p, off, 32);
        if (k == 0) d6[(size_t)bh*NN + n0 + r] = 0.6f * LOG2E * p;
    }
}

__device__ __forceinline__ u32 srfl(u32 v) { return __builtin_amdgcn_readfirstlane(v); }

// ---------------- Kernel A: scores. 256 thr (4 waves), 4 rows/wave, NC=2 j-chunks.
// No LDS, no barriers. xj = 4x dwordx4 straight from L2 (f16 rows, XCD-pinned).
// Packed f16 math: pk_add + abs-mask + v_dot2_f32_f16. P=f16 2^(e-8) + f32 lsum parts.
__global__ __launch_bounds__(256) void gat_score_kernel(const f16* __restrict__ xh,
                                                        const float* __restrict__ d6,
                                                        const int* __restrict__ adj,
                                                        const float* __restrict__ Wa,
                                                        f16* __restrict__ P,
                                                        float* __restrict__ lsp) {
    const int tid = threadIdx.x;
    const int w = __builtin_amdgcn_readfirstlane(tid >> 6);   // wave 0..3
    const int l = tid & 63;
    const int blk = blockIdx.x;                // 0..1023
    const int bh = blk & 7;                    // XCD pin
    const int rest = blk >> 3;                 // 0..127
    const int jc = rest & (NC - 1);
    const int i0 = (rest >> 1) << 4;           // 16 rows per block
    const int h = bh & 3, b = bh >> 2;
    const int ib = i0 + 4*w;                   // wave's first row

    const u32* xhu = (const u32*)(xh + (size_t)bh*NN*HID);    // 16 u32 per row
    const float* dbh = d6 + (size_t)bh*NN;

    // wa packed h2, pre-scaled by 0.4*log2e -> SGPRs
    u32 wa2[16];
    {
        const float* wap = Wa + h*HID;
#pragma unroll
        for (int q = 0; q < 16; ++q) {
            h2 hw;
            hw[0] = (f16)((0.4f*LOG2E) * wap[2*q]);
            hw[1] = (f16)((0.4f*LOG2E) * wap[2*q+1]);
            wa2[q] = srfl(bcast<u32>(hw));
        }
    }
    // 4 rows of xi packed h2 -> SGPRs; ci = d6 - 8 (fixed softmax shift)
    u32 xi2[4][16];
    float ci[4];
#pragma unroll
    for (int r = 0; r < 4; ++r) {
        const u32* xr = xhu + (size_t)(ib + r)*16;
#pragma unroll
        for (int q = 0; q < 16; ++q) xi2[r][q] = srfl(xr[q]);
        ci[r] = __uint_as_float(srfl(__float_as_uint(dbh[ib + r]))) - 8.0f;
    }

    const int* adj0 = adj + ((size_t)b*NN + ib + 0)*NN;
    const int* adj1 = adj + ((size_t)b*NN + ib + 1)*NN;
    const int* adj2 = adj + ((size_t)b*NN + ib + 2)*NN;
    const int* adj3 = adj + ((size_t)b*NN + ib + 3)*NN;
    f16* pr0 = P + ((size_t)bh << 20) + (size_t)(ib + 0)*NN;
    f16* pr1 = P + ((size_t)bh << 20) + (size_t)(ib + 1)*NN;
    f16* pr2 = P + ((size_t)bh << 20) + (size_t)(ib + 2)*NN;
    f16* pr3 = P + ((size_t)bh << 20) + (size_t)(ib + 3)*NN;

    float ls0 = 0.f, ls1 = 0.f, ls2 = 0.f, ls3 = 0.f;

    for (int tt = 0; tt < CT; ++tt) {
        const int j = (jc*CT + tt)*TJ + l;
        u64 m0 = __ballot(adj0[j] > 0);
        u64 m1 = __ballot(adj1[j] > 0);
        u64 m2 = __ballot(adj2[j] > 0);
        u64 m3 = __ballot(adj3[j] > 0);
        float dj = dbh[j];

        const u32* xjp = xhu + (size_t)j*16;
        uint4 xa = *(const uint4*)(xjp);
        uint4 xb = *(const uint4*)(xjp + 4);
        uint4 xc = *(const uint4*)(xjp + 8);
        uint4 xd = *(const uint4*)(xjp + 12);
        u32 xj[16] = {xa.x, xa.y, xa.z, xa.w, xb.x, xb.y, xb.z, xb.w,
                      xc.x, xc.y, xc.z, xc.w, xd.x, xd.y, xd.z, xd.w};

        float s0 = 0.f, s1 = 0.f, s2 = 0.f, s3 = 0.f;
#pragma unroll
        for (int q = 0; q < 16; ++q) {
            h2 xjh = bcast<h2>(xj[q]);
            h2 wq  = bcast<h2>(wa2[q]);
            h2 v; u32 a;
            v = bcast<h2>(xi2[0][q]) + xjh; a = bcast<u32>(v) & 0x7fff7fffu;
            s0 = FDOT2(bcast<h2>(a), wq, s0);
            v = bcast<h2>(xi2[1][q]) + xjh; a = bcast<u32>(v) & 0x7fff7fffu;
            s1 = FDOT2(bcast<h2>(a), wq, s1);
            v = bcast<h2>(xi2[2][q]) + xjh; a = bcast<u32>(v) & 0x7fff7fffu;
            s2 = FDOT2(bcast<h2>(a), wq, s2);
            v = bcast<h2>(xi2[3][q]) + xjh; a = bcast<u32>(v) & 0x7fff7fffu;
            s3 = FDOT2(bcast<h2>(a), wq, s3);
        }
        float p0 = exp2f(ci[0] + dj + s0);
        float p1 = exp2f(ci[1] + dj + s1);
        float p2 = exp2f(ci[2] + dj + s2);
        float p3 = exp2f(ci[3] + dj + s3);
        asm("v_cndmask_b32 %0, 0, %1, %2" : "=v"(p0) : "v"(p0), "s"(m0));
        asm("v_cndmask_b32 %0, 0, %1, %2" : "=v"(p1) : "v"(p1), "s"(m1));
        asm("v_cndmask_b32 %0, 0, %1, %2" : "=v"(p2) : "v"(p2), "s"(m2));
        asm("v_cndmask_b32 %0, 0, %1, %2" : "=v"(p3) : "v"(p3), "s"(m3));
        ls0 += p0; ls1 += p1; ls2 += p2; ls3 += p3;
        pr0[j] = (f16)p0;
        pr1[j] = (f16)p1;
        pr2[j] = (f16)p2;
        pr3[j] = (f16)p3;
    }

    // per-chunk denominator partials
#pragma unroll
    for (int off = 32; off >= 1; off >>= 1) {
        ls0 += __shfl_xor(ls0, off, 64);
        ls1 += __shfl_xor(ls1, off, 64);
        ls2 += __shfl_xor(ls2, off, 64);
        ls3 += __shfl_xor(ls3, off, 64);
    }
    if (l == 0) {
        float* lp = lsp + (size_t)jc*(8*NN) + bh*NN + ib;
        lp[0] = ls0; lp[1] = ls1; lp[2] = ls2; lp[3] = ls3;
    }
}

// ---------------- Kernel B: out = (P @ X) / lsum via MFMA f16, K=1024 (R14-verbatim).
__global__ __launch_bounds__(64) void gat_agg_kernel(const f16* __restrict__ P,
                                                     const f16* __restrict__ xt,
                                                     const float* __restrict__ lsp,
                                                     float* __restrict__ out) {
    const int l = threadIdx.x;
    const int blk = blockIdx.x;                // 0..511
    const int bh = blk & 7;                    // XCD pin (same as score)
    const int it = blk >> 3;                   // i-tile 0..63
    const int i0 = it << 4;
    const int b = bh >> 2, h = bh & 3;

    const f16* Pb  = P  + ((size_t)bh << 20);
    const f16* xtb = xt + (size_t)bh * HID * NN;

    f32x4 acc0 = {0.f, 0.f, 0.f, 0.f};
    f32x4 acc1 = {0.f, 0.f, 0.f, 0.f};
    const int lrow = l & 15, lslot = (l >> 4) << 3;

#pragma unroll
    for (int jt = 0; jt < 32; ++jt) {
        const int joff = jt*32 + lslot;
        f16x8 af = *(const f16x8*)(Pb  + (size_t)(i0 + lrow)*NN + joff);
        f16x8 b0 = *(const f16x8*)(xtb + (size_t)lrow*NN + joff);
        f16x8 b1 = *(const f16x8*)(xtb + (size_t)(16 + lrow)*NN + joff);
        acc0 = __builtin_amdgcn_mfma_f32_16x16x32_f16(af, b0, acc0, 0, 0, 0);
        acc1 = __builtin_amdgcn_mfma_f32_16x16x32_f16(af, b1, acc1, 0, 0, 0);
    }

    // C/D mapping (HW-verified): col=lane&15, row=(lane>>4)*4+reg
#pragma unroll
    for (int r = 0; r < 4; ++r) {
        int row = i0 + ((l >> 4) << 2) + r;
        float ls = lsp[bh*NN + row] + lsp[8*NN + bh*NN + row];   // jc=0 + jc=1
        float inv = 1.0f / ls;
        float* orow = out + ((size_t)(b*NN + row))*(HH*HID) + h*HID;
        orow[lrow]      = acc0[r] * inv;
        orow[16 + lrow] = acc1[r] * inv;
    }
}

extern "C" void kernel_launch(void* const* d_in, const int* in_sizes, int n_in,
                              void* d_out, int out_size, void* d_ws, size_t ws_size,
                              hipStream_t stream) {
    const float* node_feat = (const float*)d_in[0];
    const int*   adj_mtx   = (const int*)d_in[1];
    const float* W         = (const float*)d_in[2];
    const float* Wa        = (const float*)d_in[3];
    float* out = (float*)d_out;

    char* ws = (char*)d_ws;
    f16*   xh_ws = (f16*)(ws + WS_XH);
    float* d6_ws = (float*)(ws + WS_D6);
    f16*   xt_ws = (f16*)(ws + WS_XT);
    f16*   P_ws  = (f16*)(ws + WS_P);
    float* ls_ws = (float*)(ws + WS_LS);

    hipLaunchKernelGGL(gat_proj_kernel, dim3(BB*NN/4), dim3(128), 0, stream,
                       node_feat, W, Wa, xh_ws, xt_ws, d6_ws);
    hipLaunchKernelGGL(gat_score_kernel, dim3(8 * (NN/16) * NC), dim3(256), 0, stream,
                       xh_ws, d6_ws, adj_mtx, Wa, P_ws, ls_ws);
    hipLaunchKernelGGL(gat_agg_kernel, dim3(8 * (NN/16)), dim3(64), 0, stream,
                       P_ws, xt_ws, ls_ws, out);
}

// Round 16
// 37.209 us; speedup vs baseline: 1.8087x; 1.0699x over previous
//
#include <hip/hip_runtime.h>
#include <math.h>

#define BB 2
#define NN 1024
#define HH 4
#define F_IN 128
#define HID 32
#define TJ 64
#define NT 16

#define LOG2E 1.44269504f

typedef unsigned long long u64;
typedef unsigned int u32;
typedef _Float16 f16;
typedef _Float16 h2    __attribute__((ext_vector_type(2)));
typedef _Float16 f16x4 __attribute__((ext_vector_type(4)));
typedef _Float16 f16x8 __attribute__((ext_vector_type(8)));
typedef float f32x4 __attribute__((ext_vector_type(4)));

// ---- workspace layout (bytes) ----
#define WS_XH  0           // f16 x  [bh][n][k=32]   = 524288
#define WS_D6  524288      // f32 d6 [bh][n]         = 32768
#define WS_XT  557056      // f16 X^T[bh][k=32][n]   = 524288

#if __has_builtin(__builtin_amdgcn_fdot2)
#define FDOT2(a, b, c) __builtin_amdgcn_fdot2((a), (b), (c), false)
#else
static __device__ __forceinline__ float FDOT2(h2 a, h2 b, float c) {
    return fmaf((float)a[0], (float)b[0], fmaf((float)a[1], (float)b[1], c));
}
#endif

template <typename D, typename S>
static __device__ __forceinline__ D bcast(S s) { return __builtin_bit_cast(D, s); }

// ---------------- Kernel 1: proj (x=feat@W) -> xh(f16 [n][k]) + xt(f16 [k][n]) + d6
// (R15-verbatim)
__global__ __launch_bounds__(128) void gat_proj_kernel(const float* __restrict__ feat,
        const float* __restrict__ W, const float* __restrict__ Wa,
        f16* __restrict__ xh, f16* __restrict__ xt, float* __restrict__ d6) {
    const int RPB = 4;
    int blk = blockIdx.x;              // 0 .. BB*NN/4-1
    int b  = blk / (NN / RPB);
    int n0 = (blk % (NN / RPB)) * RPB;
    int t  = threadIdx.x;              // 0..127 -> output column h*32+k

    __shared__ float fs[RPB][F_IN];
#pragma unroll
    for (int e = 0; e < RPB; ++e) {
        int idx = e * 128 + t;
        int r = idx >> 7, f = idx & 127;
        fs[r][f] = feat[((size_t)(b*NN + n0 + r))*F_IN + f];
    }
    __syncthreads();

    float acc[RPB];
#pragma unroll
    for (int r = 0; r < RPB; ++r) acc[r] = 0.f;
    for (int f = 0; f < F_IN; ++f) {
        float w = W[f*(HH*HID) + t];
#pragma unroll
        for (int r = 0; r < RPB; ++r) acc[r] = fmaf(fs[r][f], w, acc[r]);
    }

    int h = t >> 5, k = t & 31;
    int bh = b*HH + h;
#pragma unroll
    for (int r = 0; r < RPB; ++r)
        xh[((size_t)bh*NN + n0 + r)*HID + k] = (f16)acc[r];
    {
        f16x4 hv;
#pragma unroll
        for (int r = 0; r < RPB; ++r) hv[r] = (f16)acc[r];
        *(f16x4*)(xt + ((size_t)bh*HID + k)*NN + n0) = hv;
    }
    float w_t = Wa[t];
#pragma unroll
    for (int r = 0; r < RPB; ++r) {
        float p = acc[r] * w_t;
#pragma unroll
        for (int off = 16; off >= 1; off >>= 1) p += __shfl_xor(p, off, 32);
        if (k == 0) d6[(size_t)bh*NN + n0 + r] = 0.6f * LOG2E * p;
    }
}

__device__ __forceinline__ u32 srfl(u32 v) { return __builtin_amdgcn_readfirstlane(v); }

// ---------------- Kernel 2: FUSED score + MFMA aggregation.
// 512 thr (8 waves) per block; block = (bh, 16-row i-tile); full j range (NC=1).
// Phase 1 (score): wave w owns rows 2w,2w+1. R15 packed-f16 core; P -> LDS f16
// [16][1032] (pad 8 -> 2-way reads); exact in-wave lsum.
// Phase 2 (agg): 8 waves x 4 jt MFMA steps from LDS-P (A) + global xt (B);
// partial C reduced via 9-padded LDS scratch; divide by 1/lsum; write out.
__global__ __launch_bounds__(512) void gat_fused_kernel(const f16* __restrict__ xh,
                                                        const float* __restrict__ d6,
                                                        const int* __restrict__ adj,
                                                        const float* __restrict__ Wa,
                                                        const f16* __restrict__ xt,
                                                        float* __restrict__ out) {
    const int tid = threadIdx.x;
    const int w = __builtin_amdgcn_readfirstlane(tid >> 6);   // wave 0..7
    const int l = tid & 63;
    const int blk = blockIdx.x;                // 0..511
    const int bh = blk & 7;                    // XCD pin
    const int i0 = (blk >> 3) << 4;            // 16 rows per block
    const int h = bh & 3, b = bh >> 2;
    const int rA = 2*w, rB = 2*w + 1;          // local rows
    const int iA = i0 + rA, iB = i0 + rB;

    const u32* xhu = (const u32*)(xh + (size_t)bh*NN*HID);    // 16 u32 per row
    const float* dbh = d6 + (size_t)bh*NN;

    __shared__ __align__(16) f16 Pl[16][1032]; // 33.0 KB (pad 8)
    __shared__ float scr[8][64][9];            // 18.4 KB (pad 9)
    __shared__ float lsinv[16];

    // ---- prologue: packed wa + 2 rows of xi -> SGPRs (R15 pattern)
    u32 wa2[16];
    {
        const float* wap = Wa + h*HID;
#pragma unroll
        for (int q = 0; q < 16; ++q) {
            h2 hw;
            hw[0] = (f16)((0.4f*LOG2E) * wap[2*q]);
            hw[1] = (f16)((0.4f*LOG2E) * wap[2*q+1]);
            wa2[q] = srfl(bcast<u32>(hw));
        }
    }
    u32 xiA[16], xiB[16];
    {
        const u32* xrA = xhu + (size_t)iA*16;
        const u32* xrB = xhu + (size_t)iB*16;
#pragma unroll
        for (int q = 0; q < 16; ++q) { xiA[q] = srfl(xrA[q]); xiB[q] = srfl(xrB[q]); }
    }
    float ciA = __uint_as_float(srfl(__float_as_uint(dbh[iA]))) - 8.0f;
    float ciB = __uint_as_float(srfl(__float_as_uint(dbh[iB]))) - 8.0f;

    const int* adjA = adj + ((size_t)b*NN + iA)*NN;
    const int* adjB = adj + ((size_t)b*NN + iB)*NN;

    float lsA = 0.f, lsB = 0.f;

    // ---- phase 1: scores over all 16 tiles
    for (int tt = 0; tt < NT; ++tt) {
        const int j = tt*TJ + l;
        u64 mA = __ballot(adjA[j] > 0);
        u64 mB = __ballot(adjB[j] > 0);
        float dj = dbh[j];

        const u32* xjp = xhu + (size_t)j*16;
        uint4 xa = *(const uint4*)(xjp);
        uint4 xb = *(const uint4*)(xjp + 4);
        uint4 xc = *(const uint4*)(xjp + 8);
        uint4 xd = *(const uint4*)(xjp + 12);
        u32 xj[16] = {xa.x, xa.y, xa.z, xa.w, xb.x, xb.y, xb.z, xb.w,
                      xc.x, xc.y, xc.z, xc.w, xd.x, xd.y, xd.z, xd.w};

        float sA = 0.f, sB = 0.f;
#pragma unroll
        for (int q = 0; q < 16; ++q) {
            h2 xjh = bcast<h2>(xj[q]);
            h2 wq  = bcast<h2>(wa2[q]);
            h2 v; u32 a;
            v = bcast<h2>(xiA[q]) + xjh; a = bcast<u32>(v) & 0x7fff7fffu;
            sA = FDOT2(bcast<h2>(a), wq, sA);
            v = bcast<h2>(xiB[q]) + xjh; a = bcast<u32>(v) & 0x7fff7fffu;
            sB = FDOT2(bcast<h2>(a), wq, sB);
        }
        float pA = exp2f(ciA + dj + sA);
        float pB = exp2f(ciB + dj + sB);
        asm("v_cndmask_b32 %0, 0, %1, %2" : "=v"(pA) : "v"(pA), "s"(mA));
        asm("v_cndmask_b32 %0, 0, %1, %2" : "=v"(pB) : "v"(pB), "s"(mB));
        lsA += pA;
        lsB += pB;
        Pl[rA][j] = (f16)pA;
        Pl[rB][j] = (f16)pB;
    }

    // exact denominators (full j range) -> LDS
#pragma unroll
    for (int off = 32; off >= 1; off >>= 1) {
        lsA += __shfl_xor(lsA, off, 64);
        lsB += __shfl_xor(lsB, off, 64);
    }
    if (l == 0) { lsinv[rA] = 1.0f / lsA; lsinv[rB] = 1.0f / lsB; }
    __syncthreads();

    // ---- phase 2: MFMA agg. wave w -> jt = 4w..4w+3 (K slice), R15-validated frags.
    const f16* xtb = xt + (size_t)bh * HID * NN;
    const int lrow = l & 15, lslot = (l >> 4) << 3;

    f32x4 acc0 = {0.f, 0.f, 0.f, 0.f};
    f32x4 acc1 = {0.f, 0.f, 0.f, 0.f};
#pragma unroll
    for (int q = 0; q < 4; ++q) {
        const int joff = (w*4 + q)*32 + lslot;
        f16x8 af = *(const f16x8*)&Pl[lrow][joff];
        f16x8 b0 = *(const f16x8*)(xtb + (size_t)lrow*NN + joff);
        f16x8 b1 = *(const f16x8*)(xtb + (size_t)(16 + lrow)*NN + joff);
        acc0 = __builtin_amdgcn_mfma_f32_16x16x32_f16(af, b0, acc0, 0, 0, 0);
        acc1 = __builtin_amdgcn_mfma_f32_16x16x32_f16(af, b1, acc1, 0, 0, 0);
    }

    // partial C -> padded LDS
#pragma unroll
    for (int e = 0; e < 4; ++e) {
        scr[w][l][e]     = acc0[e];
        scr[w][l][4 + e] = acc1[e];
    }
    __syncthreads();

    // reduce 8 wave-partials; thread (w,l) handles C-slot e=w.
    // C/D mapping (HW-verified): slot e<4 -> acc0[e]: row=i0+(l>>4)*4+e, col=lrow;
    // e>=4 -> acc1[e-4]: row=i0+(l>>4)*4+(e-4), col=16+lrow.
    {
        float s = 0.f;
#pragma unroll
        for (int ww = 0; ww < 8; ++ww) s += scr[ww][l][w];
        const int r = w & 3;
        const int col = ((w >= 4) ? 16 : 0) + lrow;
        const int rloc = ((l >> 4) << 2) + r;
        const int row = i0 + rloc;
        out[((size_t)(b*NN + row))*(HH*HID) + h*HID + col] = s * lsinv[rloc];
    }
}

extern "C" void kernel_launch(void* const* d_in, const int* in_sizes, int n_in,
                              void* d_out, int out_size, void* d_ws, size_t ws_size,
                              hipStream_t stream) {
    const float* node_feat = (const float*)d_in[0];
    const int*   adj_mtx   = (const int*)d_in[1];
    const float* W         = (const float*)d_in[2];
    const float* Wa        = (const float*)d_in[3];
    float* out = (float*)d_out;

    char* ws = (char*)d_ws;
    f16*   xh_ws = (f16*)(ws + WS_XH);
    float* d6_ws = (float*)(ws + WS_D6);
    f16*   xt_ws = (f16*)(ws + WS_XT);

    hipLaunchKernelGGL(gat_proj_kernel, dim3(BB*NN/4), dim3(128), 0, stream,
                       node_feat, W, Wa, xh_ws, xt_ws, d6_ws);
    hipLaunchKernelGGL(gat_fused_kernel, dim3(8 * (NN/16)), dim3(512), 0, stream,
                       xh_ws, d6_ws, adj_mtx, Wa, xt_ws, out);
}

// Round 17
// 35.756 us; speedup vs baseline: 1.8822x; 1.0406x over previous
//
#include <hip/hip_runtime.h>
#include <math.h>

#define BB 2
#define NN 1024
#define HH 4
#define F_IN 128
#define HID 32
#define TJ 64
#define NT 16
#define CT 8           // tiles per j-half

#define LOG2E 1.44269504f

typedef unsigned long long u64;
typedef unsigned int u32;
typedef _Float16 f16;
typedef _Float16 h2    __attribute__((ext_vector_type(2)));
typedef _Float16 f16x4 __attribute__((ext_vector_type(4)));
typedef _Float16 f16x8 __attribute__((ext_vector_type(8)));
typedef float f32x4 __attribute__((ext_vector_type(4)));

// ---- workspace layout (bytes) ----
#define WS_XH  0           // f16 x  [bh][n][k=32]   = 524288
#define WS_D6  524288      // f32 d6 [bh][n]         = 32768
#define WS_XT  557056      // f16 X^T[bh][k=32][n]   = 524288

#if __has_builtin(__builtin_amdgcn_fdot2)
#define FDOT2(a, b, c) __builtin_amdgcn_fdot2((a), (b), (c), false)
#else
static __device__ __forceinline__ float FDOT2(h2 a, h2 b, float c) {
    return fmaf((float)a[0], (float)b[0], fmaf((float)a[1], (float)b[1], c));
}
#endif

template <typename D, typename S>
static __device__ __forceinline__ D bcast(S s) { return __builtin_bit_cast(D, s); }

// ---------------- Kernel 1: proj (x=feat@W) -> xh(f16 [n][k]) + xt(f16 [k][n]) + d6
// (R15/R16-verbatim)
__global__ __launch_bounds__(128) void gat_proj_kernel(const float* __restrict__ feat,
        const float* __restrict__ W, const float* __restrict__ Wa,
        f16* __restrict__ xh, f16* __restrict__ xt, float* __restrict__ d6) {
    const int RPB = 4;
    int blk = blockIdx.x;              // 0 .. BB*NN/4-1
    int b  = blk / (NN / RPB);
    int n0 = (blk % (NN / RPB)) * RPB;
    int t  = threadIdx.x;              // 0..127 -> output column h*32+k

    __shared__ float fs[RPB][F_IN];
#pragma unroll
    for (int e = 0; e < RPB; ++e) {
        int idx = e * 128 + t;
        int r = idx >> 7, f = idx & 127;
        fs[r][f] = feat[((size_t)(b*NN + n0 + r))*F_IN + f];
    }
    __syncthreads();

    float acc[RPB];
#pragma unroll
    for (int r = 0; r < RPB; ++r) acc[r] = 0.f;
    for (int f = 0; f < F_IN; ++f) {
        float w = W[f*(HH*HID) + t];
#pragma unroll
        for (int r = 0; r < RPB; ++r) acc[r] = fmaf(fs[r][f], w, acc[r]);
    }

    int h = t >> 5, k = t & 31;
    int bh = b*HH + h;
#pragma unroll
    for (int r = 0; r < RPB; ++r)
        xh[((size_t)bh*NN + n0 + r)*HID + k] = (f16)acc[r];
    {
        f16x4 hv;
#pragma unroll
        for (int r = 0; r < RPB; ++r) hv[r] = (f16)acc[r];
        *(f16x4*)(xt + ((size_t)bh*HID + k)*NN + n0) = hv;
    }
    float w_t = Wa[t];
#pragma unroll
    for (int r = 0; r < RPB; ++r) {
        float p = acc[r] * w_t;
#pragma unroll
        for (int off = 16; off >= 1; off >>= 1) p += __shfl_xor(p, off, 32);
        if (k == 0) d6[(size_t)bh*NN + n0 + r] = 0.6f * LOG2E * p;
    }
}

__device__ __forceinline__ u32 srfl(u32 v) { return __builtin_amdgcn_readfirstlane(v); }

// ---------------- Kernel 2: FUSED score + MFMA aggregation.
// 512 thr (8 waves); block = (bh, 16-row i-tile).
// Phase 1 (R15 4-row packed core, j-split): wave w -> row-quad q=w&3 (rows 4q..4q+3),
// j-half hf=w>>2 (8 tiles). Barrier-free; P -> LDS [16][1032]; half-range lsum
// partials -> lsp2[2][16].
// Phase 2 (R16-verbatim): 8 waves x 4 jt MFMA from LDS-P (A) + global xt (B);
// scr-reduce; divide by combined lsum; write out.
__global__ __launch_bounds__(512) void gat_fused_kernel(const f16* __restrict__ xh,
                                                        const float* __restrict__ d6,
                                                        const int* __restrict__ adj,
                                                        const float* __restrict__ Wa,
                                                        const f16* __restrict__ xt,
                                                        float* __restrict__ out) {
    const int tid = threadIdx.x;
    const int w = __builtin_amdgcn_readfirstlane(tid >> 6);   // wave 0..7
    const int l = tid & 63;
    const int blk = blockIdx.x;                // 0..511
    const int bh = blk & 7;                    // XCD pin
    const int i0 = (blk >> 3) << 4;            // 16 rows per block
    const int h = bh & 3, b = bh >> 2;
    const int q4 = w & 3, hf = w >> 2;         // row-quad, j-half
    const int ib = i0 + 4*q4;                  // wave's first row

    const u32* xhu = (const u32*)(xh + (size_t)bh*NN*HID);    // 16 u32 per row
    const float* dbh = d6 + (size_t)bh*NN;

    __shared__ __align__(16) f16 Pl[16][1032]; // 33.0 KB (pad 8)
    __shared__ float scr[8][64][9];            // 18.4 KB (pad 9)
    __shared__ float lsp2[2][16];              // half-range lsum partials

    // ---- prologue (R15-verbatim): packed wa + 4 rows of xi -> SGPRs
    u32 wa2[16];
    {
        const float* wap = Wa + h*HID;
#pragma unroll
        for (int q = 0; q < 16; ++q) {
            h2 hw;
            hw[0] = (f16)((0.4f*LOG2E) * wap[2*q]);
            hw[1] = (f16)((0.4f*LOG2E) * wap[2*q+1]);
            wa2[q] = srfl(bcast<u32>(hw));
        }
    }
    u32 xi2[4][16];
    float ci[4];
#pragma unroll
    for (int r = 0; r < 4; ++r) {
        const u32* xr = xhu + (size_t)(ib + r)*16;
#pragma unroll
        for (int q = 0; q < 16; ++q) xi2[r][q] = srfl(xr[q]);
        ci[r] = __uint_as_float(srfl(__float_as_uint(dbh[ib + r]))) - 8.0f;
    }

    const int* adj0 = adj + ((size_t)b*NN + ib + 0)*NN;
    const int* adj1 = adj + ((size_t)b*NN + ib + 1)*NN;
    const int* adj2 = adj + ((size_t)b*NN + ib + 2)*NN;
    const int* adj3 = adj + ((size_t)b*NN + ib + 3)*NN;

    float ls0 = 0.f, ls1 = 0.f, ls2 = 0.f, ls3 = 0.f;

    // ---- phase 1: scores over this wave's j-half (R15 core)
    for (int tt = 0; tt < CT; ++tt) {
        const int j = (hf*CT + tt)*TJ + l;
        u64 m0 = __ballot(adj0[j] > 0);
        u64 m1 = __ballot(adj1[j] > 0);
        u64 m2 = __ballot(adj2[j] > 0);
        u64 m3 = __ballot(adj3[j] > 0);
        float dj = dbh[j];

        const u32* xjp = xhu + (size_t)j*16;
        uint4 xa = *(const uint4*)(xjp);
        uint4 xb = *(const uint4*)(xjp + 4);
        uint4 xc = *(const uint4*)(xjp + 8);
        uint4 xd = *(const uint4*)(xjp + 12);
        u32 xj[16] = {xa.x, xa.y, xa.z, xa.w, xb.x, xb.y, xb.z, xb.w,
                      xc.x, xc.y, xc.z, xc.w, xd.x, xd.y, xd.z, xd.w};

        float s0 = 0.f, s1 = 0.f, s2 = 0.f, s3 = 0.f;
#pragma unroll
        for (int q = 0; q < 16; ++q) {
            h2 xjh = bcast<h2>(xj[q]);
            h2 wq  = bcast<h2>(wa2[q]);
            h2 v; u32 a;
            v = bcast<h2>(xi2[0][q]) + xjh; a = bcast<u32>(v) & 0x7fff7fffu;
            s0 = FDOT2(bcast<h2>(a), wq, s0);
            v = bcast<h2>(xi2[1][q]) + xjh; a = bcast<u32>(v) & 0x7fff7fffu;
            s1 = FDOT2(bcast<h2>(a), wq, s1);
            v = bcast<h2>(xi2[2][q]) + xjh; a = bcast<u32>(v) & 0x7fff7fffu;
            s2 = FDOT2(bcast<h2>(a), wq, s2);
            v = bcast<h2>(xi2[3][q]) + xjh; a = bcast<u32>(v) & 0x7fff7fffu;
            s3 = FDOT2(bcast<h2>(a), wq, s3);
        }
        float p0 = exp2f(ci[0] + dj + s0);
        float p1 = exp2f(ci[1] + dj + s1);
        float p2 = exp2f(ci[2] + dj + s2);
        float p3 = exp2f(ci[3] + dj + s3);
        asm("v_cndmask_b32 %0, 0, %1, %2" : "=v"(p0) : "v"(p0), "s"(m0));
        asm("v_cndmask_b32 %0, 0, %1, %2" : "=v"(p1) : "v"(p1), "s"(m1));
        asm("v_cndmask_b32 %0, 0, %1, %2" : "=v"(p2) : "v"(p2), "s"(m2));
        asm("v_cndmask_b32 %0, 0, %1, %2" : "=v"(p3) : "v"(p3), "s"(m3));
        ls0 += p0; ls1 += p1; ls2 += p2; ls3 += p3;
        Pl[4*q4 + 0][j] = (f16)p0;
        Pl[4*q4 + 1][j] = (f16)p1;
        Pl[4*q4 + 2][j] = (f16)p2;
        Pl[4*q4 + 3][j] = (f16)p3;
    }

    // half-range denominator partials -> LDS
#pragma unroll
    for (int off = 32; off >= 1; off >>= 1) {
        ls0 += __shfl_xor(ls0, off, 64);
        ls1 += __shfl_xor(ls1, off, 64);
        ls2 += __shfl_xor(ls2, off, 64);
        ls3 += __shfl_xor(ls3, off, 64);
    }
    if (l == 0) {
        lsp2[hf][4*q4 + 0] = ls0;
        lsp2[hf][4*q4 + 1] = ls1;
        lsp2[hf][4*q4 + 2] = ls2;
        lsp2[hf][4*q4 + 3] = ls3;
    }
    __syncthreads();

    // ---- phase 2 (R16-verbatim): MFMA agg. wave w -> jt = 4w..4w+3 (K slice).
    const f16* xtb = xt + (size_t)bh * HID * NN;
    const int lrow = l & 15, lslot = (l >> 4) << 3;

    f32x4 acc0 = {0.f, 0.f, 0.f, 0.f};
    f32x4 acc1 = {0.f, 0.f, 0.f, 0.f};
#pragma unroll
    for (int q = 0; q < 4; ++q) {
        const int joff = (w*4 + q)*32 + lslot;
        f16x8 af = *(const f16x8*)&Pl[lrow][joff];
        f16x8 b0 = *(const f16x8*)(xtb + (size_t)lrow*NN + joff);
        f16x8 b1 = *(const f16x8*)(xtb + (size_t)(16 + lrow)*NN + joff);
        acc0 = __builtin_amdgcn_mfma_f32_16x16x32_f16(af, b0, acc0, 0, 0, 0);
        acc1 = __builtin_amdgcn_mfma_f32_16x16x32_f16(af, b1, acc1, 0, 0, 0);
    }

    // partial C -> padded LDS
#pragma unroll
    for (int e = 0; e < 4; ++e) {
        scr[w][l][e]     = acc0[e];
        scr[w][l][4 + e] = acc1[e];
    }
    __syncthreads();

    // reduce 8 wave-partials; thread (w,l) handles C-slot e=w.
    // C/D mapping (HW-verified): e<4 -> acc0[e]: row=i0+(l>>4)*4+e, col=lrow;
    // e>=4 -> acc1[e-4]: row=i0+(l>>4)*4+(e-4), col=16+lrow.
    {
        float s = 0.f;
#pragma unroll
        for (int ww = 0; ww < 8; ++ww) s += scr[ww][l][w];
        const int r = w & 3;
        const int col = ((w >= 4) ? 16 : 0) + lrow;
        const int rloc = ((l >> 4) << 2) + r;
        const int row = i0 + rloc;
        float inv = 1.0f / (lsp2[0][rloc] + lsp2[1][rloc]);
        out[((size_t)(b*NN + row))*(HH*HID) + h*HID + col] = s * inv;
    }
}

extern "C" void kernel_launch(void* const* d_in, const int* in_sizes, int n_in,
                              void* d_out, int out_size, void* d_ws, size_t ws_size,
                              hipStream_t stream) {
    const float* node_feat = (const float*)d_in[0];
    const int*   adj_mtx   = (const int*)d_in[1];
    const float* W         = (const float*)d_in[2];
    const float* Wa        = (const float*)d_in[3];
    float* out = (float*)d_out;

    char* ws = (char*)d_ws;
    f16*   xh_ws = (f16*)(ws + WS_XH);
    float* d6_ws = (float*)(ws + WS_D6);
    f16*   xt_ws = (f16*)(ws + WS_XT);

    hipLaunchKernelGGL(gat_proj_kernel, dim3(BB*NN/4), dim3(128), 0, stream,
                       node_feat, W, Wa, xh_ws, xt_ws, d6_ws);
    hipLaunchKernelGGL(gat_fused_kernel, dim3(8 * (NN/16)), dim3(512), 0, stream,
                       xh_ws, d6_ws, adj_mtx, Wa, xt_ws, out);
}